// Round 1
// baseline (173.968 us; speedup 1.0000x reference)
//
#include <hip/hip_runtime.h>
#include <math.h>

#define B_  32
#define NS_ 50
#define NQ_ 75
#define T_  128
#define F_  64
#define D_  256
#define K_  5
#define NR_ (NS_ + NQ_)   // 125 rows per episode (supports then queries)
#define QT_ 5             // query tile per stage-2 block (75 = 15 * 5)
#define NTILE_ 15

typedef float v4f __attribute__((ext_vector_type(4)));

// ---------------------------------------------------------------------------
// Stage 1: time-mean pool + PROJECTION, one wave per item.
// Mean-pool part identical to the verified R2 kernel (contiguous 1 KB/instr
// nontemporal wave reads, 2 shuffle rounds). New: since the encoder is
// affine, z = mean_t(x)·W + b is computed here directly. Each lane owns
// d = 4*lane..4*lane+3: 64 L2-resident float4 loads of W rows + 256 FMA.
// W (64 KB) is reused by all 4000 items -> stays hot in every XCD's L2;
// input stream stays nontemporal so it never evicts W.
// Output: zbuf [B*NR, 256] = 4 MB (vs 1 MB of F-space means before).
// ---------------------------------------------------------------------------
__global__ __launch_bounds__(256) void meanproj_kernel(
    const float* __restrict__ sx, const float* __restrict__ qx,
    const float* __restrict__ Wm, const float* __restrict__ bias,
    float* __restrict__ zbuf)
{
    __shared__ float mean_s[4][F_];   // per-wave time-mean (64 floats each)

    const int wave = threadIdx.x >> 6, lane = threadIdx.x & 63;
    const int item = blockIdx.x * 4 + wave;        // 0 .. B*NR-1
    const int b = item / NR_, n = item % NR_;
    const float* src = (n < NS_)
        ? (sx + (size_t)(b * NS_ + n) * (T_ * F_))
        : (qx + (size_t)(b * NQ_ + (n - NS_)) * (T_ * F_));
    const v4f* src4 = (const v4f*)src;

    v4f a0 = 0.f, a1 = 0.f, a2 = 0.f, a3 = 0.f;
#pragma unroll
    for (int s = 0; s < 32; s += 4) {
        v4f v0 = __builtin_nontemporal_load(&src4[(s + 0) * 64 + lane]);
        v4f v1 = __builtin_nontemporal_load(&src4[(s + 1) * 64 + lane]);
        v4f v2 = __builtin_nontemporal_load(&src4[(s + 2) * 64 + lane]);
        v4f v3 = __builtin_nontemporal_load(&src4[(s + 3) * 64 + lane]);
        a0 += v0; a1 += v1; a2 += v2; a3 += v3;
    }
    v4f a = (a0 + a1) + (a2 + a3);

    a.x += __shfl_down(a.x, 32); a.y += __shfl_down(a.y, 32);
    a.z += __shfl_down(a.z, 32); a.w += __shfl_down(a.w, 32);
    a.x += __shfl_down(a.x, 16); a.y += __shfl_down(a.y, 16);
    a.z += __shfl_down(a.z, 16); a.w += __shfl_down(a.w, 16);

    if (lane < 16)
        ((v4f*)mean_s[wave])[lane] = a * (1.f / T_);
    __syncthreads();   // cheap; guarantees LDS mean visible (waves arrive together)

    // projection: lane owns d = 4*lane..4*lane+3; two accumulators break the
    // serial FMA dependence; W4[f*64+lane] is a coalesced 1 KB wave read (L2 hit)
    const v4f* W4 = (const v4f*)Wm;                 // W[f][d]: W4[f*64 + lane]
    const float* ms = mean_s[wave];
    v4f accA = ((const v4f*)bias)[lane];
    v4f accB = 0.f;
#pragma unroll
    for (int f = 0; f < F_; f += 2) {
        accA += ms[f]     * W4[(f    ) * 64 + lane];
        accB += ms[f + 1] * W4[(f + 1) * 64 + lane];
    }
    ((v4f*)zbuf)[(size_t)item * 64 + lane] = accA + accB;
}

// ---------------------------------------------------------------------------
// Stage 2: one block per (episode, query-tile of 5). 480 blocks, 256 threads.
// Now projection-free: label-mean the 50 support z-rows (thread d = tid owns
// column d -> fully coalesced, all 256 threads active vs 64 before), then
// 25 (q,k) shuffle-reduced Euclidean distances over D=256. No W, no wreg[64].
// ---------------------------------------------------------------------------
__global__ __launch_bounds__(256) void dist_kernel(
    const float* __restrict__ zbuf, const int* __restrict__ sy,
    float* __restrict__ out)
{
    __shared__ float qz[QT_][D_];
    __shared__ float pz[K_][D_];
    __shared__ int   labels[NS_];
    __shared__ int   counts[K_];

    const int tid = threadIdx.x;
    const int bid = blockIdx.x;            // 0 .. B*NTILE-1
    const int b = bid / NTILE_, qt = bid % NTILE_;
    const int q0 = qt * QT_;
    const float* zb = zbuf + (size_t)b * NR_ * D_;

    if (tid < NS_) labels[tid] = sy[b * NS_ + tid];
    // query rows: independent of labels, load before the barrier
#pragma unroll
    for (int r = 0; r < QT_; ++r)
        qz[r][tid] = zb[(NS_ + q0 + r) * D_ + tid];
    __syncthreads();

    if (tid < K_) {
        int c = 0;
        for (int s = 0; s < NS_; ++s) c += (labels[s] == tid);
        counts[tid] = c;
    }

    // label-grouped sums over support z-rows; thread d = tid, coalesced loads
    {
        const int d = tid;
        float p0 = 0.f, p1 = 0.f, p2 = 0.f, p3 = 0.f, p4 = 0.f;
        for (int s = 0; s < NS_; ++s) {
            float v = zb[s * D_ + d];
            int l = labels[s];
            if      (l == 0) p0 += v;
            else if (l == 1) p1 += v;
            else if (l == 2) p2 += v;
            else if (l == 3) p3 += v;
            else             p4 += v;
        }
        __syncthreads();   // counts ready
        pz[0][d] = p0 / (float)counts[0];
        pz[1][d] = p1 / (float)counts[1];
        pz[2][d] = p2 / (float)counts[2];
        pz[3][d] = p3 / (float)counts[3];
        pz[4][d] = p4 / (float)counts[4];
    }
    __syncthreads();

    // distances: 25 (q,k) pairs striped over 4 waves
    const int wave = tid >> 6, lane = tid & 63;
    for (int p = wave; p < QT_ * K_; p += 4) {
        const int q = p / K_, k = p % K_;
        float s = 0.f;
#pragma unroll
        for (int j = 0; j < 4; ++j) {
            int d = lane + j * 64;
            float diff = qz[q][d] - pz[k][d];
            s += diff * diff;
        }
        for (int off = 32; off > 0; off >>= 1) s += __shfl_down(s, off);
        if (lane == 0) out[(size_t)(b * NQ_ + q0 + q) * K_ + k] = -sqrtf(s);
    }
}

extern "C" void kernel_launch(void* const* d_in, const int* in_sizes, int n_in,
                              void* d_out, int out_size, void* d_ws, size_t ws_size,
                              hipStream_t stream) {
    const float* sx   = (const float*)d_in[0];   // support_x [32,50,128,64]
    const int*   sy   = (const int*)  d_in[1];   // support_y [32,50]
    const float* qx   = (const float*)d_in[2];   // query_x   [32,75,128,64]
    const float* Wm   = (const float*)d_in[3];   // W [64,256]
    const float* bias = (const float*)d_in[4];   // b [256]
    float* out  = (float*)d_out;                 // [2400, 5]
    float* zbuf = (float*)d_ws;                  // B*125*256 floats = 4.0 MB

    meanproj_kernel<<<(B_ * NR_) / 4, 256, 0, stream>>>(sx, qx, Wm, bias, zbuf);
    dist_kernel<<<B_ * NTILE_, 256, 0, stream>>>(zbuf, sy, out);
}